// Round 3
// baseline (246.760 us; speedup 1.0000x reference)
//
#include <hip/hip_runtime.h>
#include <hip/hip_bf16.h>

#define LOG2PI 1.8378770664093453f

// N=16384, M=4096, K=64.
// OutW columns: 0-63 z_mu(dot), 64-127 c = x@Wd^T, 128 s_enc dot, 129 x.b_dec,
// 130 sum(x^2), 131-143 pad. Stride 144.
// Bp chunk layout: chunk idx (kq*144 + c), kq=0..511 (8 k-floats each), see pack_b.

typedef __attribute__((ext_vector_type(8))) short bf16x8;
typedef __attribute__((ext_vector_type(4))) float f32x4;

__device__ __forceinline__ unsigned short f2bf(float f) {
    unsigned int u = __builtin_bit_cast(unsigned int, f);
    u += 0x7FFFu + ((u >> 16) & 1u);
    return (unsigned short)(u >> 16);
}
__device__ __forceinline__ short f2bf_s(float f) {
    return (short)__builtin_bit_cast(unsigned short, __float2bfloat16(f));
}

// ---------------- pack B into MFMA-fragment-ordered bf16 chunks
__global__ __launch_bounds__(256) void pack_b_kernel(const float* __restrict__ We,
        const float* __restrict__ Wes, const float* __restrict__ Wd,
        const float* __restrict__ bd, unsigned short* __restrict__ Bp) {
    int idx = blockIdx.x * 256 + threadIdx.x;   // kq*144 + c
    int c = idx % 144;
    int kq = idx / 144;
    int k0 = kq * 8;
    unsigned short out[8];
#pragma unroll
    for (int j = 0; j < 8; ++j) {
        int m = k0 + j;
        float v = 0.f;
        if (c < 64)        v = We[(size_t)m * 64 + c];
        else if (c < 128)  v = Wd[(size_t)(c - 64) * 4096 + m];
        else if (c == 128) v = Wes[m];
        else if (c == 129) v = bd[m];
        out[j] = f2bf(v);
    }
    *reinterpret_cast<uint4*>(Bp + (size_t)idx * 8) = *reinterpret_cast<uint4*>(out);
}

// ---------------- G = Wd Wd^T, h = Wd @ bd, e = sum(bd^2)
__global__ void prep_g_kernel(const float* __restrict__ Wd, const float* __restrict__ bd,
                              float* __restrict__ G, float* __restrict__ hv,
                              float* __restrict__ ev) {
    __shared__ float red[256];
    int a = blockIdx.x, t = threadIdx.x;
    int col = t & 63, seg = t >> 6;
    const float* ra = Wd + (size_t)a * 4096;
    const float* rc = Wd + (size_t)col * 4096;
    float p = 0.f;
    int j0 = seg * 1024;
    for (int j = 0; j < 1024; ++j) p = fmaf(ra[j0 + j], rc[j0 + j], p);
    red[t] = p;
    __syncthreads();
    if (t < 64) G[a * 64 + t] = red[t] + red[t + 64] + red[t + 128] + red[t + 192];
    __syncthreads();
    float ph = 0.f;
    for (int j = t; j < 4096; j += 256) ph = fmaf(ra[j], bd[j], ph);
    red[t] = ph;
    __syncthreads();
    for (int s = 128; s > 0; s >>= 1) { if (t < s) red[t] += red[t + s]; __syncthreads(); }
    if (t == 0) hv[a] = red[0];
    if (a == 0) {
        __syncthreads();
        float pe = 0.f;
        for (int j = t; j < 4096; j += 256) { float b = bd[j]; pe = fmaf(b, b, pe); }
        red[t] = pe;
        __syncthreads();
        for (int s = 128; s > 0; s >>= 1) { if (t < s) red[t] += red[t + s]; __syncthreads(); }
        if (t == 0) ev[0] = red[0];
    }
}

// ---------------- main GEMM: 2 waves/block, k-split, wave-private LDS transpose
__global__ __launch_bounds__(128, 2) void gemm_kernel(const float* __restrict__ x,
        const unsigned short* __restrict__ Bp, float* __restrict__ OutW) {
    __shared__ __align__(16) char lds[16384];   // 2 waves x 2 bufs x 4096 B (+ reuse for combine)
    const int tid = threadIdx.x;
    const int lane = tid & 63, w = tid >> 6;
    const int l15 = lane & 15, kg = lane >> 4;
    const int rowbase = blockIdx.x * 16;
    char* myLds = lds + w * 8192;
    const int kw = w * 64;                       // this wave's first kt (of 128 total)

    // A global base: lane loads contiguous float4s of row (rowbase + lane>>2)
    const float* xbase = x + (size_t)(rowbase + (lane >> 2)) * 4096 + w * 2048 + (lane & 3) * 4;
    const bf16x8* bch = reinterpret_cast<const bf16x8*>(Bp);

    // precomputed swizzled LDS write offsets: r = lane>>2, u = s*4 + (lane&3)
    int wr_off[4];
    {
        int r = lane >> 2, e = lane & 3;
#pragma unroll
        for (int s = 0; s < 4; ++s) wr_off[s] = r * 256 + (((s * 4 + e) ^ r) << 4);
    }
    const int rd_base = l15 * 256;

    f32x4 acc[9];
#pragma unroll
    for (int i = 0; i < 9; ++i) acc[i] = (f32x4){0.f, 0.f, 0.f, 0.f};
    float sx2 = 0.f;

    float4 g0[4], g1[4];
    bf16x8 b0[9], b1[9];

#define GLOAD(ch, g) do { \
        _Pragma("unroll") \
        for (int s_ = 0; s_ < 4; ++s_) \
            g[s_] = *reinterpret_cast<const float4*>(xbase + (ch) * 64 + s_ * 16); \
    } while (0)
#define WRLDS(buf, g) do { \
        _Pragma("unroll") \
        for (int s_ = 0; s_ < 4; ++s_) \
            *reinterpret_cast<float4*>(myLds + (buf) * 4096 + wr_off[s_]) = g[s_]; \
    } while (0)
#define LDB(ktg, d) do { \
        const bf16x8* p_ = bch + ((size_t)((ktg) * 4 + kg) * 144 + l15); \
        _Pragma("unroll") \
        for (int ni_ = 0; ni_ < 9; ++ni_) d[ni_] = p_[ni_ * 16]; \
    } while (0)
#define KTSTEP(buf, kkt, bb) do { \
        const int u0_ = (kkt) * 8 + kg * 2; \
        f32x4 fa_ = *reinterpret_cast<f32x4*>(myLds + (buf) * 4096 + rd_base + (((u0_) ^ l15) << 4)); \
        f32x4 fb_ = *reinterpret_cast<f32x4*>(myLds + (buf) * 4096 + rd_base + (((u0_ + 1) ^ l15) << 4)); \
        bf16x8 af_; \
        af_[0] = f2bf_s(fa_[0]); af_[1] = f2bf_s(fa_[1]); \
        af_[2] = f2bf_s(fa_[2]); af_[3] = f2bf_s(fa_[3]); \
        af_[4] = f2bf_s(fb_[0]); af_[5] = f2bf_s(fb_[1]); \
        af_[6] = f2bf_s(fb_[2]); af_[7] = f2bf_s(fb_[3]); \
        sx2 += fa_[0]*fa_[0] + fa_[1]*fa_[1] + fa_[2]*fa_[2] + fa_[3]*fa_[3] \
             + fb_[0]*fb_[0] + fb_[1]*fb_[1] + fb_[2]*fb_[2] + fb_[3]*fb_[3]; \
        _Pragma("unroll") \
        for (int ni_ = 0; ni_ < 9; ++ni_) \
            acc[ni_] = __builtin_amdgcn_mfma_f32_16x16x32_bf16(af_, bb[ni_], acc[ni_], 0, 0, 0); \
    } while (0)

    // prologue: LDS[0] <- chunk0; g1 <- chunk1; g0 <- chunk2 (in flight); b0 <- kt0
    GLOAD(0, g0);
    GLOAD(1, g1);
    LDB(kw + 0, b0);
    WRLDS(0, g0);
    GLOAD(2, g0);

    for (int ch = 0; ch < 32; ch += 2) {
        // BODY even: LDS[0] ready; g1 holds ch+1; g0 in flight (ch+2)
        LDB(kw + ch * 2 + 1, b1);
        KTSTEP(0, 0, b0);
        if (ch < 31) LDB(kw + ch * 2 + 2, b0);
        KTSTEP(0, 1, b1);
        if (ch < 31) WRLDS(1, g1);
        if (ch < 29) GLOAD(ch + 3, g1);
        // BODY odd: LDS[1] ready; g0 holds ch+2; g1 in flight (ch+3)
        LDB(kw + ch * 2 + 3, b1);
        KTSTEP(1, 0, b0);
        if (ch + 1 < 31) LDB(kw + ch * 2 + 4, b0);
        KTSTEP(1, 1, b1);
        if (ch + 1 < 31) WRLDS(0, g0);
        if (ch + 1 < 29) GLOAD(ch + 4, g0);
    }
#undef GLOAD
#undef WRLDS
#undef LDB
#undef KTSTEP

    // reduce sx2 across the 4 kg groups holding the same row (within wave)
    sx2 += __shfl_xor(sx2, 16);
    sx2 += __shfl_xor(sx2, 32);

    // combine the two k-halves: wave 1 -> LDS, wave 0 adds and stores
    __syncthreads();
    float* fs = reinterpret_cast<float*>(lds);          // [16][144]
    float* fs2 = reinterpret_cast<float*>(lds) + 2304;  // [16]
    if (w == 1) {
#pragma unroll
        for (int ni = 0; ni < 9; ++ni)
#pragma unroll
            for (int i = 0; i < 4; ++i)
                fs[(kg * 4 + i) * 144 + ni * 16 + l15] = acc[ni][i];
        if (lane < 16) fs2[lane] = sx2;
    }
    __syncthreads();
    if (w == 0) {
#pragma unroll
        for (int ni = 0; ni < 9; ++ni) {
            int col = ni * 16 + l15;
            if (col < 130) {
#pragma unroll
                for (int i = 0; i < 4; ++i)
                    OutW[(size_t)(rowbase + kg * 4 + i) * 144 + col] =
                        acc[ni][i] + fs[(kg * 4 + i) * 144 + col];
            }
        }
        if (lane < 16)
            OutW[(size_t)(rowbase + lane) * 144 + 130] = sx2 + fs2[lane];
    }
}

// ---------------- phase 2: one wave per row-pair, K=64 = 64 lanes
__global__ __launch_bounds__(256) void phase2_kernel(const float* __restrict__ OutW,
        const float* __restrict__ noise, const float* __restrict__ bem,
        const float* __restrict__ Wds, const float* __restrict__ bes_p,
        const float* __restrict__ bds_p, const float* __restrict__ G,
        const float* __restrict__ hv, const float* __restrict__ ev,
        float* __restrict__ partial) {
    __shared__ float Gl[4096];
    __shared__ float hl[64], wl[64], beml[64];
    __shared__ float red[4];
    int tid = threadIdx.x;
    for (int i = tid; i < 4096; i += 256) Gl[i] = G[i];
    if (tid < 64) { hl[tid] = hv[tid]; wl[tid] = Wds[tid]; beml[tid] = bem[tid]; }
    __syncthreads();
    float bes = bes_p[0], bds = bds_p[0], e = ev[0];
    int wid = tid >> 6, k = tid & 63;
    float wacc = 0.f;
#pragma unroll
    for (int rr = 0; rr < 2; ++rr) {
        int row = blockIdx.x * 8 + wid * 2 + rr;
        const float* orow = OutW + (size_t)row * 144;
        float zmu = orow[k] + beml[k];
        float ck  = orow[64 + k];
        float se  = orow[128] + bes;
        float dd  = orow[129];
        float sx2 = orow[130];
        float nz  = noise[(size_t)row * 64 + k];
        float s2 = se * se;
        float z = fmaf(s2, nz, zmu);
        float t0 = 0.f, t1 = 0.f, t2 = 0.f, t3 = 0.f;
#pragma unroll
        for (int kp = 0; kp < 64; kp += 4) {
            t0 = fmaf(Gl[(kp + 0) * 64 + k], __shfl(z, kp + 0), t0);
            t1 = fmaf(Gl[(kp + 1) * 64 + k], __shfl(z, kp + 1), t1);
            t2 = fmaf(Gl[(kp + 2) * 64 + k], __shfl(z, kp + 2), t2);
            t3 = fmaf(Gl[(kp + 3) * 64 + k], __shfl(z, kp + 3), t3);
        }
        float t = (t0 + t1) + (t2 + t3);
        float ra = z * z;
        float rb = nz * nz;
        float rc = z * wl[k];
        float rd = z * ck;
        float re = z * fmaf(2.f, hl[k], t);
#pragma unroll
        for (int d = 1; d < 64; d <<= 1) {
            ra += __shfl_xor(ra, d); rb += __shfl_xor(rb, d);
            rc += __shfl_xor(rc, d); rd += __shfl_xor(rd, d);
            re += __shfl_xor(re, d);
        }
        float sdec = rc + bds;
        float xxmu = rd + dd;
        float xmu2 = re + e;
        float sq_lik = sx2 - 2.f * xxmu + xmu2;
        float vz = s2 * s2;
        float sd2 = sdec * sdec;
        float vx = sd2 * sd2;
        wacc += 0.5f * (4096.f * LOG2PI + 4096.f * __logf(vx) + sq_lik / vx
                        + ra - 64.f * __logf(vz) - rb);
    }
    if (k == 0) red[wid] = wacc;
    __syncthreads();
    if (tid == 0) partial[blockIdx.x] = red[0] + red[1] + red[2] + red[3];
}

__global__ __launch_bounds__(256) void final_reduce_kernel(const float* __restrict__ partial,
                                                           float* __restrict__ out) {
    __shared__ float red[4];
    int tid = threadIdx.x;
    float v = 0.f;
    for (int i = tid; i < 2048; i += 256) v += partial[i];
#pragma unroll
    for (int d = 1; d < 64; d <<= 1) v += __shfl_xor(v, d);
    if ((tid & 63) == 0) red[tid >> 6] = v;
    __syncthreads();
    if (tid == 0) out[0] = red[0] + red[1] + red[2] + red[3];
}

extern "C" void kernel_launch(void* const* d_in, const int* in_sizes, int n_in,
                              void* d_out, int out_size, void* d_ws, size_t ws_size,
                              hipStream_t stream) {
    const float* x     = (const float*)d_in[0];
    const float* noise = (const float*)d_in[1];
    const float* We    = (const float*)d_in[2];
    const float* bem   = (const float*)d_in[3];
    const float* Wes   = (const float*)d_in[4];
    const float* bes   = (const float*)d_in[5];
    const float* Wd    = (const float*)d_in[6];
    const float* bdm   = (const float*)d_in[7];
    const float* Wds   = (const float*)d_in[8];
    const float* bds   = (const float*)d_in[9];

    char* ws = (char*)d_ws;
    float* OutW          = (float*)ws;                      // 9,437,184 B
    unsigned short* Bp   = (unsigned short*)(ws + 9437184); // 1,179,648 B
    float* G             = (float*)(ws + 10616832);
    float* hv            = (float*)(ws + 10633216);
    float* ev            = (float*)(ws + 10633472);
    float* partial       = (float*)(ws + 10633728);         // 8,192 B

    pack_b_kernel<<<288, 256, 0, stream>>>(We, Wes, Wd, bdm, Bp);
    prep_g_kernel<<<64, 256, 0, stream>>>(Wd, bdm, G, hv, ev);
    gemm_kernel<<<1024, 128, 0, stream>>>(x, Bp, OutW);
    phase2_kernel<<<2048, 256, 0, stream>>>(OutW, noise, bem, Wds, bes, bds, G, hv, ev, partial);
    final_reduce_kernel<<<1, 256, 0, stream>>>(partial, (float*)d_out);
}

// Round 4
// 161.240 us; speedup vs baseline: 1.5304x; 1.5304x over previous
//
#include <hip/hip_runtime.h>
#include <hip/hip_bf16.h>

#define LOG2PI 1.8378770664093453f

// N=16384, M(K-dim)=4096, K(latent)=64.
// GEMM: Out[n][c] = sum_m x[n][m] * Bcat[c][m], c in [0,160) padded (144 real):
//   c 0-63: W_enc_mu col, 64-127: W_dec_mu row (c-64), 128: W_enc_sigma, 129: b_dec_mu.
// Split-K: KSPLIT slices of the m-dimension; partials Pp[row][ks][144] (stride ppstride).
// col 130 of each partial = per-slice sum(x^2).
//
// Bp layout: per absolute k-tile kt (32 m-values), a 12288-B linear LDS image:
//   offset col*64 + u*16 holds Bcat[col][kt*32 + (u^(col&3))*8 .. +8] as 8 bf16.
// A LDS image per step: row*128 + u8*16 holds x[row][t*32 + (u8^(row&7))*4 ..+4] fp32.

typedef __attribute__((ext_vector_type(8))) short bf16x8;
typedef __attribute__((ext_vector_type(4))) float f32x4;

__device__ __forceinline__ unsigned short f2bf(float f) {
    unsigned int u = __builtin_bit_cast(unsigned int, f);
    u += 0x7FFFu + ((u >> 16) & 1u);
    return (unsigned short)(u >> 16);
}
__device__ __forceinline__ short f2bf_s(float f) {
    return (short)__builtin_bit_cast(unsigned short, __float2bfloat16(f));
}
__device__ __forceinline__ void gll16(const void* g, void* l) {
    __builtin_amdgcn_global_load_lds(
        (const __attribute__((address_space(1))) void*)g,
        (__attribute__((address_space(3))) void*)l, 16, 0, 0);
}

// ---------------- pack B: linear LDS images per k-tile (incl. XOR swizzle)
__global__ __launch_bounds__(256) void pack_b_kernel(const float* __restrict__ We,
        const float* __restrict__ Wes, const float* __restrict__ Wd,
        const float* __restrict__ bd, unsigned char* __restrict__ Bp) {
    int idx = blockIdx.x * 256 + threadIdx.x;   // [0, 98304) = kt*768 + col*4 + u
    int kt = idx / 768;
    int r = idx % 768;
    int col = r >> 2, u = r & 3;
    int ku = u ^ (col & 3);
    int k0 = kt * 32 + ku * 8;
    unsigned short out[8];
#pragma unroll
    for (int j = 0; j < 8; ++j) {
        int m = k0 + j;
        float v = 0.f;
        if (col < 64)        v = We[(size_t)m * 64 + col];
        else if (col < 128)  v = Wd[(size_t)(col - 64) * 4096 + m];
        else if (col == 128) v = Wes[m];
        else if (col == 129) v = bd[m];
        out[j] = f2bf(v);
    }
    *reinterpret_cast<uint4*>(Bp + (size_t)idx * 16) = *reinterpret_cast<uint4*>(out);
}

// ---------------- G = Wd Wd^T, h = Wd @ bd, e = sum(bd^2)
__global__ void prep_g_kernel(const float* __restrict__ Wd, const float* __restrict__ bd,
                              float* __restrict__ G, float* __restrict__ hv,
                              float* __restrict__ ev) {
    __shared__ float red[256];
    int a = blockIdx.x, t = threadIdx.x;
    int col = t & 63, seg = t >> 6;
    const float* ra = Wd + (size_t)a * 4096;
    const float* rc = Wd + (size_t)col * 4096;
    float p = 0.f;
    int j0 = seg * 1024;
    for (int j = 0; j < 1024; ++j) p = fmaf(ra[j0 + j], rc[j0 + j], p);
    red[t] = p;
    __syncthreads();
    if (t < 64) G[a * 64 + t] = red[t] + red[t + 64] + red[t + 128] + red[t + 192];
    __syncthreads();
    float ph = 0.f;
    for (int j = t; j < 4096; j += 256) ph = fmaf(ra[j], bd[j], ph);
    red[t] = ph;
    __syncthreads();
    for (int s = 128; s > 0; s >>= 1) { if (t < s) red[t] += red[t + s]; __syncthreads(); }
    if (t == 0) hv[a] = red[0];
    if (a == 0) {
        __syncthreads();
        float pe = 0.f;
        for (int j = t; j < 4096; j += 256) { float b = bd[j]; pe = fmaf(b, b, pe); }
        red[t] = pe;
        __syncthreads();
        for (int s = 128; s > 0; s >>= 1) { if (t < s) red[t] += red[t + s]; __syncthreads(); }
        if (t == 0) ev[0] = red[0];
    }
}

// ---------------- main GEMM: 2-phase template, global_load_lds, counted vmcnt
__global__ __launch_bounds__(256, 4) void gemm_kernel(const float* __restrict__ x,
        const unsigned char* __restrict__ Bp, float* __restrict__ Pp,
        int steps, int kslice, int ppstride) {
    __shared__ __align__(16) char ldsA[16384];   // 2 x (64 rows x 128 B)
    __shared__ __align__(16) char ldsB[24576];   // 2 x (192 cols x 64 B)
    const int tid = threadIdx.x;
    const int lane = tid & 63, w = tid >> 6;
    const int wm = w >> 1, wn = w & 1;           // 2m x 2n waves
    const int l15 = lane & 15, kg = lane >> 4;
    const int rowbase = blockIdx.x * 64;
    const int ks = blockIdx.y;

    // A per-lane global pointers: instr i covers rows (w*2+i)*8 + (lane>>3),
    // swizzled column unit (lane&7)^(lane>>3)
    const float* xA[2];
    {
        int rsub = lane >> 3;
        int co = ((lane & 7) ^ rsub) << 2;       // float offset within 32
#pragma unroll
        for (int i = 0; i < 2; ++i)
            xA[i] = x + (size_t)(rowbase + (w * 2 + i) * 8 + rsub) * 4096
                      + (size_t)ks * kslice + co;
    }
    const unsigned char* gB0 = Bp + (size_t)(ks * steps) * 12288
                                  + (size_t)(w * 3) * 1024 + (size_t)lane * 16;

    f32x4 acc[2][5];
#pragma unroll
    for (int mi = 0; mi < 2; ++mi)
#pragma unroll
        for (int ni = 0; ni < 5; ++ni) acc[mi][ni] = (f32x4){0.f, 0.f, 0.f, 0.f};
    float sxa0 = 0.f, sxa1 = 0.f;

#define STAGE(buf, tt) do { \
        _Pragma("unroll") \
        for (int i_ = 0; i_ < 2; ++i_) \
            gll16(xA[i_] + (tt) * 32, ldsA + (buf) * 8192 + (w * 2 + i_) * 1024); \
        _Pragma("unroll") \
        for (int j_ = 0; j_ < 3; ++j_) \
            gll16(gB0 + (size_t)(tt) * 12288 + j_ * 1024, \
                  ldsB + (buf) * 12288 + (w * 3 + j_) * 1024); \
    } while (0)

#define COMPUTE(buf) do { \
        char* A0 = ldsA + (buf) * 8192; \
        char* B0 = ldsB + (buf) * 12288; \
        bf16x8 bfr[5]; \
        _Pragma("unroll") \
        for (int ni_ = 0; ni_ < 5; ++ni_) { \
            int col_ = wn * 80 + ni_ * 16 + l15; \
            bfr[ni_] = *reinterpret_cast<const bf16x8*>( \
                B0 + col_ * 64 + ((kg ^ (col_ & 3)) << 4)); \
        } \
        _Pragma("unroll") \
        for (int mi_ = 0; mi_ < 2; ++mi_) { \
            int row_ = wm * 32 + mi_ * 16 + l15; \
            int e0_ = (kg << 1) ^ (row_ & 7); \
            f32x4 fa_ = *reinterpret_cast<const f32x4*>(A0 + row_ * 128 + (e0_ << 4)); \
            f32x4 fb_ = *reinterpret_cast<const f32x4*>(A0 + row_ * 128 + ((e0_ ^ 1) << 4)); \
            bf16x8 af_; \
            af_[0] = f2bf_s(fa_[0]); af_[1] = f2bf_s(fa_[1]); \
            af_[2] = f2bf_s(fa_[2]); af_[3] = f2bf_s(fa_[3]); \
            af_[4] = f2bf_s(fb_[0]); af_[5] = f2bf_s(fb_[1]); \
            af_[6] = f2bf_s(fb_[2]); af_[7] = f2bf_s(fb_[3]); \
            if (wn == 0) { \
                float ss_ = fa_[0]*fa_[0] + fa_[1]*fa_[1] + fa_[2]*fa_[2] + fa_[3]*fa_[3] \
                          + fb_[0]*fb_[0] + fb_[1]*fb_[1] + fb_[2]*fb_[2] + fb_[3]*fb_[3]; \
                if (mi_ == 0) sxa0 += ss_; else sxa1 += ss_; \
            } \
            _Pragma("unroll") \
            for (int ni_ = 0; ni_ < 5; ++ni_) \
                acc[mi_][ni_] = __builtin_amdgcn_mfma_f32_16x16x32_bf16( \
                    af_, bfr[ni_], acc[mi_][ni_], 0, 0, 0); \
        } \
    } while (0)

    STAGE(0, 0);
    asm volatile("s_waitcnt vmcnt(0)" ::: "memory");
    __builtin_amdgcn_s_barrier();
    asm volatile("" ::: "memory");
    int cur = 0;
    for (int t = 0; t < steps - 1; ++t) {
        STAGE(cur ^ 1, t + 1);
        asm volatile("s_waitcnt vmcnt(5)" ::: "memory");
        __builtin_amdgcn_s_barrier();
        asm volatile("" ::: "memory");
        COMPUTE(cur);
        asm volatile("" ::: "memory");
        __builtin_amdgcn_s_barrier();
        cur ^= 1;
    }
    asm volatile("s_waitcnt vmcnt(0)" ::: "memory");
    __builtin_amdgcn_s_barrier();
    asm volatile("" ::: "memory");
    COMPUTE(cur);
#undef STAGE
#undef COMPUTE

    // store partials: C layout col=lane&15, row=(lane>>4)*4+i
#pragma unroll
    for (int mi = 0; mi < 2; ++mi)
#pragma unroll
        for (int ni = 0; ni < 5; ++ni) {
            int col = wn * 80 + ni * 16 + l15;
            if (col < 130) {
#pragma unroll
                for (int i2 = 0; i2 < 4; ++i2) {
                    int row = rowbase + wm * 32 + mi * 16 + kg * 4 + i2;
                    Pp[(size_t)row * ppstride + ks * 144 + col] = acc[mi][ni][i2];
                }
            }
        }
    if (wn == 0) {
#pragma unroll
        for (int mi = 0; mi < 2; ++mi) {
            float s = (mi == 0) ? sxa0 : sxa1;
            s += __shfl_xor(s, 16);
            s += __shfl_xor(s, 32);
            if (lane < 16)
                Pp[(size_t)(rowbase + wm * 32 + mi * 16 + lane) * ppstride
                   + ks * 144 + 130] = s;
        }
    }
}

// ---------------- phase 2: 32 rows/block, symmetric-G row reads, LDS z-broadcast
__global__ __launch_bounds__(256) void phase2_kernel(const float* __restrict__ Pp,
        const float* __restrict__ noise, const float* __restrict__ bem,
        const float* __restrict__ Wds, const float* __restrict__ bes_p,
        const float* __restrict__ bds_p, const float* __restrict__ G,
        const float* __restrict__ hv, const float* __restrict__ ev,
        float* __restrict__ partial, int ksplit, int ppstride) {
    __shared__ float Gl[64 * 68];                 // padded stride 68 floats
    __shared__ float hl[64], wl[64], beml[64];
    __shared__ float zs[4][64];
    __shared__ float red[4];
    int tid = threadIdx.x;
    for (int i = tid; i < 4096; i += 256) {
        int r = i >> 6, c = i & 63;
        Gl[r * 68 + c] = G[i];
    }
    if (tid < 64) { hl[tid] = hv[tid]; wl[tid] = Wds[tid]; beml[tid] = bem[tid]; }
    __syncthreads();
    float bes = bes_p[0], bds = bds_p[0], e = ev[0];
    int wid = tid >> 6, k = tid & 63;
    float wacc = 0.f;
#pragma unroll
    for (int rr = 0; rr < 8; ++rr) {
        int row = blockIdx.x * 32 + wid * 8 + rr;
        const float* base = Pp + (size_t)row * ppstride;
        float zmu = beml[k], ck = 0.f, se = bes, dd = 0.f, sx2 = 0.f;
        for (int s = 0; s < ksplit; ++s) {
            const float* b2 = base + s * 144;
            zmu += b2[k]; ck += b2[64 + k];
            se += b2[128]; dd += b2[129]; sx2 += b2[130];
        }
        float nz = noise[(size_t)row * 64 + k];
        float s2 = se * se;
        float z = fmaf(s2, nz, zmu);
        zs[wid][k] = z;                            // wave-synchronous broadcast
        float t0 = 0.f, t1 = 0.f, t2 = 0.f, t3 = 0.f;
        const float* gr = &Gl[k * 68];
        const float* zr = &zs[wid][0];
#pragma unroll
        for (int j = 0; j < 4; ++j) {
            f32x4 g0 = *reinterpret_cast<const f32x4*>(gr + j * 16);
            f32x4 g1 = *reinterpret_cast<const f32x4*>(gr + j * 16 + 4);
            f32x4 g2 = *reinterpret_cast<const f32x4*>(gr + j * 16 + 8);
            f32x4 g3 = *reinterpret_cast<const f32x4*>(gr + j * 16 + 12);
            f32x4 z0 = *reinterpret_cast<const f32x4*>(zr + j * 16);
            f32x4 z1 = *reinterpret_cast<const f32x4*>(zr + j * 16 + 4);
            f32x4 z2 = *reinterpret_cast<const f32x4*>(zr + j * 16 + 8);
            f32x4 z3 = *reinterpret_cast<const f32x4*>(zr + j * 16 + 12);
#pragma unroll
            for (int q = 0; q < 4; ++q) {
                t0 = fmaf(g0[q], z0[q], t0); t1 = fmaf(g1[q], z1[q], t1);
                t2 = fmaf(g2[q], z2[q], t2); t3 = fmaf(g3[q], z3[q], t3);
            }
        }
        float t = (t0 + t1) + (t2 + t3);           // (Gz)_k via symmetry
        float ra = z * z;
        float rb = nz * nz;
        float rc = z * wl[k];
        float rd = z * ck;
        float re = z * fmaf(2.f, hl[k], t);
#pragma unroll
        for (int d = 1; d < 64; d <<= 1) {
            ra += __shfl_xor(ra, d); rb += __shfl_xor(rb, d);
            rc += __shfl_xor(rc, d); rd += __shfl_xor(rd, d);
            re += __shfl_xor(re, d);
        }
        float sdec = rc + bds;
        float xxmu = rd + dd;
        float xmu2 = re + e;
        float sq_lik = sx2 - 2.f * xxmu + xmu2;
        float vz = s2 * s2;
        float sd2 = sdec * sdec;
        float vx = sd2 * sd2;
        wacc += 0.5f * (4096.f * LOG2PI + 4096.f * __logf(vx) + sq_lik / vx
                        + ra - 64.f * __logf(vz) - rb);
    }
    if (k == 0) red[wid] = wacc;
    __syncthreads();
    if (tid == 0) partial[blockIdx.x] = red[0] + red[1] + red[2] + red[3];
}

__global__ __launch_bounds__(256) void final_reduce_kernel(const float* __restrict__ partial,
                                                           float* __restrict__ out) {
    __shared__ float red[4];
    int tid = threadIdx.x;
    float v = 0.f;
    for (int i = tid; i < 512; i += 256) v += partial[i];
#pragma unroll
    for (int d = 1; d < 64; d <<= 1) v += __shfl_xor(v, d);
    if ((tid & 63) == 0) red[tid >> 6] = v;
    __syncthreads();
    if (tid == 0) out[0] = red[0] + red[1] + red[2] + red[3];
}

extern "C" void kernel_launch(void* const* d_in, const int* in_sizes, int n_in,
                              void* d_out, int out_size, void* d_ws, size_t ws_size,
                              hipStream_t stream) {
    const float* x     = (const float*)d_in[0];
    const float* noise = (const float*)d_in[1];
    const float* We    = (const float*)d_in[2];
    const float* bem   = (const float*)d_in[3];
    const float* Wes   = (const float*)d_in[4];
    const float* bes   = (const float*)d_in[5];
    const float* Wd    = (const float*)d_in[6];
    const float* bdm   = (const float*)d_in[7];
    const float* Wds   = (const float*)d_in[8];
    const float* bds   = (const float*)d_in[9];

    // need(ks) = 16384*ks*144*4 + 1.5M(Bp) + G/hv/ev/partial
    int ksplit = (ws_size >= 39340544ull) ? 4 : (ws_size >= 20466176ull ? 2 : 1);
    int steps = 128 / ksplit;
    int kslice = steps * 32;
    int ppstride = ksplit * 144;

    char* ws = (char*)d_ws;
    size_t ppbytes = (size_t)16384 * ppstride * 4;
    float* Pp           = (float*)ws;
    unsigned char* Bp   = (unsigned char*)(ws + ppbytes);
    float* G            = (float*)(ws + ppbytes + 1572864);
    float* hv           = (float*)(ws + ppbytes + 1572864 + 16384);
    float* ev           = (float*)(ws + ppbytes + 1572864 + 16640);
    float* partial      = (float*)(ws + ppbytes + 1572864 + 16896);

    pack_b_kernel<<<384, 256, 0, stream>>>(We, Wes, Wd, bdm, Bp);
    prep_g_kernel<<<64, 256, 0, stream>>>(Wd, bdm, G, hv, ev);
    gemm_kernel<<<dim3(256, ksplit), 256, 0, stream>>>(x, Bp, Pp, steps, kslice, ppstride);
    phase2_kernel<<<512, 256, 0, stream>>>(Pp, noise, bem, Wds, bes, bds, G, hv, ev,
                                           partial, ksplit, ppstride);
    final_reduce_kernel<<<1, 256, 0, stream>>>(partial, (float*)d_out);
}

// Round 5
// 156.170 us; speedup vs baseline: 1.5801x; 1.0325x over previous
//
#include <hip/hip_runtime.h>
#include <hip/hip_bf16.h>

#define LOG2PI 1.8378770664093453f

// N=16384, M(K-dim)=4096, K(latent)=64.
// GEMM: Out[n][c] = sum_m x[n][m] * Bcat[c][m], c padded to 192 (144 real):
//   c 0-63: W_enc_mu col, 64-127: W_dec_mu row (c-64), 128: W_enc_sigma, 129: b_dec_mu.
// Split-K: KSPLIT slices of m; partials Pp[row][ks][144] (stride ppstride).
// col 130 of each partial = per-slice sum(x^2); cols 131-143 zero.
//
// Bp layout: per k-tile kt (32 m-values), a 12288-B linear LDS image:
//   offset col*64 + u*16 holds Bcat[col][kt*32 + (u^(col&3))*8 .. +8] as 8 bf16.
// A LDS image per step: row*128 + u8*16 holds x[row][t*32 + (u8^(row&7))*4 ..+4] fp32.

typedef __attribute__((ext_vector_type(8))) short bf16x8;
typedef __attribute__((ext_vector_type(4))) float f32x4;

__device__ __forceinline__ unsigned short f2bf(float f) {
    unsigned int u = __builtin_bit_cast(unsigned int, f);
    u += 0x7FFFu + ((u >> 16) & 1u);
    return (unsigned short)(u >> 16);
}
__device__ __forceinline__ short f2bf_s(float f) {
    return (short)__builtin_bit_cast(unsigned short, __float2bfloat16(f));
}
__device__ __forceinline__ void gll16(const void* g, void* l) {
    __builtin_amdgcn_global_load_lds(
        (const __attribute__((address_space(1))) void*)g,
        (__attribute__((address_space(3))) void*)l, 16, 0, 0);
}

// ---------------- pack B: linear LDS images per k-tile (incl. XOR swizzle)
__global__ __launch_bounds__(256) void pack_b_kernel(const float* __restrict__ We,
        const float* __restrict__ Wes, const float* __restrict__ Wd,
        const float* __restrict__ bd, unsigned char* __restrict__ Bp) {
    int idx = blockIdx.x * 256 + threadIdx.x;   // [0, 98304) = kt*768 + col*4 + u
    int kt = idx / 768;
    int r = idx % 768;
    int col = r >> 2, u = r & 3;
    int ku = u ^ (col & 3);
    int k0 = kt * 32 + ku * 8;
    unsigned short out[8];
#pragma unroll
    for (int j = 0; j < 8; ++j) {
        int m = k0 + j;
        float v = 0.f;
        if (col < 64)        v = We[(size_t)m * 64 + col];
        else if (col < 128)  v = Wd[(size_t)(col - 64) * 4096 + m];
        else if (col == 128) v = Wes[m];
        else if (col == 129) v = bd[m];
        out[j] = f2bf(v);
    }
    *reinterpret_cast<uint4*>(Bp + (size_t)idx * 16) = *reinterpret_cast<uint4*>(out);
}

// ---------------- G = Wd Wd^T, h = Wd @ bd, e = sum(bd^2)
__global__ void prep_g_kernel(const float* __restrict__ Wd, const float* __restrict__ bd,
                              float* __restrict__ G, float* __restrict__ hv,
                              float* __restrict__ ev) {
    __shared__ float red[256];
    int a = blockIdx.x, t = threadIdx.x;
    int col = t & 63, seg = t >> 6;
    const float* ra = Wd + (size_t)a * 4096;
    const float* rc = Wd + (size_t)col * 4096;
    float p = 0.f;
    int j0 = seg * 1024;
    for (int j = 0; j < 1024; ++j) p = fmaf(ra[j0 + j], rc[j0 + j], p);
    red[t] = p;
    __syncthreads();
    if (t < 64) G[a * 64 + t] = red[t] + red[t + 64] + red[t + 128] + red[t + 192];
    __syncthreads();
    float ph = 0.f;
    for (int j = t; j < 4096; j += 256) ph = fmaf(ra[j], bd[j], ph);
    red[t] = ph;
    __syncthreads();
    for (int s = 128; s > 0; s >>= 1) { if (t < s) red[t] += red[t + s]; __syncthreads(); }
    if (t == 0) hv[a] = red[0];
    if (a == 0) {
        __syncthreads();
        float pe = 0.f;
        for (int j = t; j < 4096; j += 256) { float b = bd[j]; pe = fmaf(b, b, pe); }
        red[t] = pe;
        __syncthreads();
        for (int s = 128; s > 0; s >>= 1) { if (t < s) red[t] += red[t + s]; __syncthreads(); }
        if (t == 0) ev[0] = red[0];
    }
}

// ---------------- main GEMM: 2-phase template + coalesced LDS-staged writeback
__global__ __launch_bounds__(256, 4) void gemm_kernel(const float* __restrict__ x,
        const unsigned char* __restrict__ Bp, float* __restrict__ Pp,
        int steps, int kslice, int ppstride) {
    __shared__ __align__(16) char lds[40960];    // A: 2x8192 @0, B: 2x12288 @16384; C-tile reuse
    char* ldsA = lds;
    char* ldsB = lds + 16384;
    const int tid = threadIdx.x;
    const int lane = tid & 63, w = tid >> 6;
    const int wm = w >> 1, wn = w & 1;           // 2m x 2n waves
    const int l15 = lane & 15, kg = lane >> 4;
    const int rowbase = blockIdx.x * 64;
    const int ks = blockIdx.y;

    const float* xA[2];
    {
        int rsub = lane >> 3;
        int co = ((lane & 7) ^ rsub) << 2;
#pragma unroll
        for (int i = 0; i < 2; ++i)
            xA[i] = x + (size_t)(rowbase + (w * 2 + i) * 8 + rsub) * 4096
                      + (size_t)ks * kslice + co;
    }
    const unsigned char* gB0 = Bp + (size_t)(ks * steps) * 12288
                                  + (size_t)(w * 3) * 1024 + (size_t)lane * 16;

    f32x4 acc[2][5];
#pragma unroll
    for (int mi = 0; mi < 2; ++mi)
#pragma unroll
        for (int ni = 0; ni < 5; ++ni) acc[mi][ni] = (f32x4){0.f, 0.f, 0.f, 0.f};
    float sxa0 = 0.f, sxa1 = 0.f;

#define STAGE(buf, tt) do { \
        _Pragma("unroll") \
        for (int i_ = 0; i_ < 2; ++i_) \
            gll16(xA[i_] + (tt) * 32, ldsA + (buf) * 8192 + (w * 2 + i_) * 1024); \
        _Pragma("unroll") \
        for (int j_ = 0; j_ < 3; ++j_) \
            gll16(gB0 + (size_t)(tt) * 12288 + j_ * 1024, \
                  ldsB + (buf) * 12288 + (w * 3 + j_) * 1024); \
    } while (0)

#define COMPUTE(buf) do { \
        char* A0 = ldsA + (buf) * 8192; \
        char* B0 = ldsB + (buf) * 12288; \
        bf16x8 bfr[5]; \
        _Pragma("unroll") \
        for (int ni_ = 0; ni_ < 5; ++ni_) { \
            int col_ = wn * 80 + ni_ * 16 + l15; \
            bfr[ni_] = *reinterpret_cast<const bf16x8*>( \
                B0 + col_ * 64 + ((kg ^ (col_ & 3)) << 4)); \
        } \
        _Pragma("unroll") \
        for (int mi_ = 0; mi_ < 2; ++mi_) { \
            int row_ = wm * 32 + mi_ * 16 + l15; \
            int e0_ = (kg << 1) ^ (row_ & 7); \
            f32x4 fa_ = *reinterpret_cast<const f32x4*>(A0 + row_ * 128 + (e0_ << 4)); \
            f32x4 fb_ = *reinterpret_cast<const f32x4*>(A0 + row_ * 128 + ((e0_ ^ 1) << 4)); \
            bf16x8 af_; \
            af_[0] = f2bf_s(fa_[0]); af_[1] = f2bf_s(fa_[1]); \
            af_[2] = f2bf_s(fa_[2]); af_[3] = f2bf_s(fa_[3]); \
            af_[4] = f2bf_s(fb_[0]); af_[5] = f2bf_s(fb_[1]); \
            af_[6] = f2bf_s(fb_[2]); af_[7] = f2bf_s(fb_[3]); \
            if (wn == 0) { \
                float ss_ = fa_[0]*fa_[0] + fa_[1]*fa_[1] + fa_[2]*fa_[2] + fa_[3]*fa_[3] \
                          + fb_[0]*fb_[0] + fb_[1]*fb_[1] + fb_[2]*fb_[2] + fb_[3]*fb_[3]; \
                if (mi_ == 0) sxa0 += ss_; else sxa1 += ss_; \
            } \
            _Pragma("unroll") \
            for (int ni_ = 0; ni_ < 5; ++ni_) \
                acc[mi_][ni_] = __builtin_amdgcn_mfma_f32_16x16x32_bf16( \
                    af_, bfr[ni_], acc[mi_][ni_], 0, 0, 0); \
        } \
    } while (0)

    STAGE(0, 0);
    asm volatile("s_waitcnt vmcnt(0)" ::: "memory");
    __builtin_amdgcn_s_barrier();
    asm volatile("" ::: "memory");
    int cur = 0;
    for (int t = 0; t < steps - 1; ++t) {
        STAGE(cur ^ 1, t + 1);
        asm volatile("s_waitcnt vmcnt(5)" ::: "memory");
        __builtin_amdgcn_s_barrier();
        asm volatile("" ::: "memory");
        COMPUTE(cur);
        asm volatile("" ::: "memory");
        __builtin_amdgcn_s_barrier();
        cur ^= 1;
    }
    asm volatile("s_waitcnt vmcnt(0)" ::: "memory");
    __builtin_amdgcn_s_barrier();
    asm volatile("" ::: "memory");
    COMPUTE(cur);
#undef STAGE
#undef COMPUTE

    // reduce sx2 across kg groups (lanes 0-15 end with row totals)
    sxa0 += __shfl_xor(sxa0, 16); sxa0 += __shfl_xor(sxa0, 32);
    sxa1 += __shfl_xor(sxa1, 16); sxa1 += __shfl_xor(sxa1, 32);

    // ---- coalesced writeback: acc -> LDS C-tile [64][148], then full rows out
    __syncthreads();
    float* C = reinterpret_cast<float*>(lds);
#pragma unroll
    for (int mi = 0; mi < 2; ++mi)
#pragma unroll
        for (int ni = 0; ni < 5; ++ni) {
            int col = wn * 80 + ni * 16 + l15;
            if (col < 148 && col != 130) {
#pragma unroll
                for (int i2 = 0; i2 < 4; ++i2)
                    C[(wm * 32 + mi * 16 + kg * 4 + i2) * 148 + col] = acc[mi][ni][i2];
            }
        }
    if (wn == 0 && lane < 16) {
        C[(wm * 32 + lane) * 148 + 130] = sxa0;
        C[(wm * 32 + 16 + lane) * 148 + 130] = sxa1;
    }
    __syncthreads();
    // 64 rows x 36 float4 = 2304 stores, 9 per thread, consecutive threads -> consecutive 16B
#pragma unroll
    for (int i = 0; i < 9; ++i) {
        int idx = tid + 256 * i;
        int r = idx / 36, c4 = idx % 36;
        f32x4 v = *reinterpret_cast<const f32x4*>(C + r * 148 + c4 * 4);
        *reinterpret_cast<f32x4*>(Pp + (size_t)(rowbase + r) * ppstride + ks * 144 + c4 * 4) = v;
    }
}

// ---------------- phase 2: plain [64][64] G, XOR-permuted conflict-free matvec
__global__ __launch_bounds__(256) void phase2_kernel(const float* __restrict__ Pp,
        const float* __restrict__ noise, const float* __restrict__ bem,
        const float* __restrict__ Wds, const float* __restrict__ bes_p,
        const float* __restrict__ bds_p, const float* __restrict__ G,
        const float* __restrict__ hv, const float* __restrict__ ev,
        float* __restrict__ partial, int ksplit, int ppstride) {
    __shared__ float Gl[4096];                    // [64][64] plain
    __shared__ float hl[64], wl[64], beml[64];
    __shared__ float zs[4][64];
    __shared__ float red[4];
    int tid = threadIdx.x;
    for (int i = tid; i < 4096; i += 256) Gl[i] = G[i];
    if (tid < 64) { hl[tid] = hv[tid]; wl[tid] = Wds[tid]; beml[tid] = bem[tid]; }
    __syncthreads();
    float bes = bes_p[0], bds = bds_p[0], e = ev[0];
    int wid = tid >> 6, k = tid & 63;
    const int sw = (k & 15) << 2;                 // per-lane permuted block order
    float wacc = 0.f;
#pragma unroll
    for (int rr = 0; rr < 8; ++rr) {
        int row = blockIdx.x * 32 + wid * 8 + rr;
        const float* base = Pp + (size_t)row * ppstride;
        float zmu = beml[k], ck = 0.f, se = bes, dd = 0.f, sx2 = 0.f;
        for (int s = 0; s < ksplit; ++s) {
            const float* b2 = base + s * 144;
            zmu += b2[k]; ck += b2[64 + k];
            se += b2[128]; dd += b2[129]; sx2 += b2[130];
        }
        float nz = noise[(size_t)row * 64 + k];
        float s2 = se * se;
        float z = fmaf(s2, nz, zmu);
        zs[wid][k] = z;                            // wave-synchronous broadcast
        float t0 = 0.f, t1 = 0.f, t2 = 0.f, t3 = 0.f;
        const float* gr = &Gl[k * 64];
        const float* zr = &zs[wid][0];
#pragma unroll
        for (int jb = 0; jb < 16; ++jb) {
            int p = (jb * 4) ^ sw;                 // banks tile 2/bank per quarter-wave
            f32x4 gv = *reinterpret_cast<const f32x4*>(gr + p);
            f32x4 zv = *reinterpret_cast<const f32x4*>(zr + p);
            t0 = fmaf(gv[0], zv[0], t0); t1 = fmaf(gv[1], zv[1], t1);
            t2 = fmaf(gv[2], zv[2], t2); t3 = fmaf(gv[3], zv[3], t3);
        }
        float t = (t0 + t1) + (t2 + t3);           // (Gz)_k via symmetry
        float ra = z * z;
        float rb = nz * nz;
        float rc = z * wl[k];
        float rd = z * ck;
        float re = z * fmaf(2.f, hl[k], t);
#pragma unroll
        for (int d = 1; d < 64; d <<= 1) {
            ra += __shfl_xor(ra, d); rb += __shfl_xor(rb, d);
            rc += __shfl_xor(rc, d); rd += __shfl_xor(rd, d);
            re += __shfl_xor(re, d);
        }
        float sdec = rc + bds;
        float xxmu = rd + dd;
        float xmu2 = re + e;
        float sq_lik = sx2 - 2.f * xxmu + xmu2;
        float vz = s2 * s2;
        float sd2 = sdec * sdec;
        float vx = sd2 * sd2;
        wacc += 0.5f * (4096.f * LOG2PI + 4096.f * __logf(vx) + sq_lik / vx
                        + ra - 64.f * __logf(vz) - rb);
    }
    if (k == 0) red[wid] = wacc;
    __syncthreads();
    if (tid == 0) partial[blockIdx.x] = red[0] + red[1] + red[2] + red[3];
}

__global__ __launch_bounds__(256) void final_reduce_kernel(const float* __restrict__ partial,
                                                           float* __restrict__ out) {
    __shared__ float red[4];
    int tid = threadIdx.x;
    float v = 0.f;
    for (int i = tid; i < 512; i += 256) v += partial[i];
#pragma unroll
    for (int d = 1; d < 64; d <<= 1) v += __shfl_xor(v, d);
    if ((tid & 63) == 0) red[tid >> 6] = v;
    __syncthreads();
    if (tid == 0) out[0] = red[0] + red[1] + red[2] + red[3];
}

extern "C" void kernel_launch(void* const* d_in, const int* in_sizes, int n_in,
                              void* d_out, int out_size, void* d_ws, size_t ws_size,
                              hipStream_t stream) {
    const float* x     = (const float*)d_in[0];
    const float* noise = (const float*)d_in[1];
    const float* We    = (const float*)d_in[2];
    const float* bem   = (const float*)d_in[3];
    const float* Wes   = (const float*)d_in[4];
    const float* bes   = (const float*)d_in[5];
    const float* Wd    = (const float*)d_in[6];
    const float* bdm   = (const float*)d_in[7];
    const float* Wds   = (const float*)d_in[8];
    const float* bds   = (const float*)d_in[9];

    int ksplit = (ws_size >= 39340544ull) ? 4 : (ws_size >= 20466176ull ? 2 : 1);
    int steps = 128 / ksplit;
    int kslice = steps * 32;
    int ppstride = ksplit * 144;

    char* ws = (char*)d_ws;
    size_t ppbytes = (size_t)16384 * ppstride * 4;
    float* Pp           = (float*)ws;
    unsigned char* Bp   = (unsigned char*)(ws + ppbytes);
    float* G            = (float*)(ws + ppbytes + 1572864);
    float* hv           = (float*)(ws + ppbytes + 1572864 + 16384);
    float* ev           = (float*)(ws + ppbytes + 1572864 + 16640);
    float* partial      = (float*)(ws + ppbytes + 1572864 + 16896);

    pack_b_kernel<<<384, 256, 0, stream>>>(We, Wes, Wd, bdm, Bp);
    prep_g_kernel<<<64, 256, 0, stream>>>(Wd, bdm, G, hv, ev);
    gemm_kernel<<<dim3(256, ksplit), 256, 0, stream>>>(x, Bp, Pp, steps, kslice, ppstride);
    phase2_kernel<<<512, 256, 0, stream>>>(Pp, noise, bem, Wds, bes, bds, G, hv, ev,
                                           partial, ksplit, ppstride);
    final_reduce_kernel<<<1, 256, 0, stream>>>(partial, (float*)d_out);
}

// Round 6
// 122.533 us; speedup vs baseline: 2.0138x; 1.2745x over previous
//
#include <hip/hip_runtime.h>
#include <hip/hip_bf16.h>

#define LOG2PI 1.8378770664093453f

// N=16384, M(K-dim)=4096, K(latent)=64.
// GEMM: Out[n][c] = sum_m x[n][m] * Bcat[c][m], c padded to 192 (144 real):
//   c 0-63: W_enc_mu col, 64-127: W_dec_mu row (c-64), 128: W_enc_sigma, 129: b_dec_mu.
// Split-K: KSPLIT slices of m; partials Pp[row][ks][144] (stride ppstride).
// col 130 of each partial = per-slice sum(x^2); cols 131-143 zero.
//
// Bp layout: per k-tile kt (32 m-values), a 12288-B linear LDS image:
//   offset col*64 + u*16 holds Bcat[col][kt*32 + (u^(col&3))*8 .. +8] as 8 bf16.
// A LDS image per step: row*128 + u8*16 holds x[row][t*32 + (u8^(row&7))*4 ..+4] fp32.

typedef __attribute__((ext_vector_type(8))) short bf16x8;
typedef __attribute__((ext_vector_type(4))) float f32x4;

__device__ __forceinline__ unsigned short f2bf(float f) {
    unsigned int u = __builtin_bit_cast(unsigned int, f);
    u += 0x7FFFu + ((u >> 16) & 1u);
    return (unsigned short)(u >> 16);
}
__device__ __forceinline__ short f2bf_s(float f) {
    return (short)__builtin_bit_cast(unsigned short, __float2bfloat16(f));
}
__device__ __forceinline__ void gll16(const void* g, void* l) {
    __builtin_amdgcn_global_load_lds(
        (const __attribute__((address_space(1))) void*)g,
        (__attribute__((address_space(3))) void*)l, 16, 0, 0);
}

// ---------------- pack B (coalesced): one block per k-tile of 32 m-values
__global__ __launch_bounds__(256) void pack_b_kernel(const float* __restrict__ We,
        const float* __restrict__ Wes, const float* __restrict__ Wd,
        const float* __restrict__ bd, unsigned char* __restrict__ Bp) {
    __shared__ float WeL[2048];   // [32 m][64 c]
    __shared__ float WdL[2048];   // [64 r][32 m]
    __shared__ float WesL[32], bdL[32];
    const int kt = blockIdx.x;    // [0,128)
    const int t = threadIdx.x;
    // stage We slab: contiguous 8 KB
#pragma unroll
    for (int i = 0; i < 2; ++i) {
        int q = t + 256 * i;
        *reinterpret_cast<f32x4*>(WeL + q * 4) =
            *reinterpret_cast<const f32x4*>(We + (size_t)kt * 2048 + q * 4);
    }
    // stage Wd slab: 64 rows x 32 floats (128-B contiguous per row)
#pragma unroll
    for (int i = 0; i < 2; ++i) {
        int f = t + 256 * i;
        int r = f >> 3, s4 = f & 7;
        *reinterpret_cast<f32x4*>(WdL + r * 32 + s4 * 4) =
            *reinterpret_cast<const f32x4*>(Wd + (size_t)r * 4096 + kt * 32 + s4 * 4);
    }
    if (t < 8) {
        *reinterpret_cast<f32x4*>(WesL + t * 4) =
            *reinterpret_cast<const f32x4*>(Wes + kt * 32 + t * 4);
    } else if (t < 16) {
        int q = t - 8;
        *reinterpret_cast<f32x4*>(bdL + q * 4) =
            *reinterpret_cast<const f32x4*>(bd + kt * 32 + q * 4);
    }
    __syncthreads();
#pragma unroll
    for (int i = 0; i < 3; ++i) {
        int cidx = t + 256 * i;            // [0,768) = col*4 + u
        int col = cidx >> 2, u = cidx & 3;
        int ku = u ^ (col & 3);
        unsigned short out[8];
#pragma unroll
        for (int j = 0; j < 8; ++j) {
            int ml = ku * 8 + j;
            float v = 0.f;
            if (col < 64)        v = WeL[ml * 64 + col];
            else if (col < 128)  v = WdL[(col - 64) * 32 + ml];
            else if (col == 128) v = WesL[ml];
            else if (col == 129) v = bdL[ml];
            out[j] = f2bf(v);
        }
        *reinterpret_cast<uint4*>(Bp + ((size_t)kt * 768 + cidx) * 16) =
            *reinterpret_cast<uint4*>(out);
    }
}

// ---------------- prep (coalesced): G pairs + h + e via row-dot blocks
__global__ __launch_bounds__(256) void prep_g_kernel(const float* __restrict__ Wd,
        const float* __restrict__ bd, float* __restrict__ G,
        float* __restrict__ hv, float* __restrict__ ev) {
    __shared__ float red[256];
    const int b = blockIdx.x, t = threadIdx.x;
    float p = 0.f;
    if (b < 4096) {
        int a = b >> 6, c = b & 63;
        const f32x4* ra = reinterpret_cast<const f32x4*>(Wd + (size_t)a * 4096);
        const f32x4* rc = reinterpret_cast<const f32x4*>(Wd + (size_t)c * 4096);
        for (int j = t; j < 1024; j += 256) {
            f32x4 u = ra[j], v = rc[j];
            p += u[0] * v[0] + u[1] * v[1] + u[2] * v[2] + u[3] * v[3];
        }
    } else if (b < 4160) {
        int a = b - 4096;
        const f32x4* ra = reinterpret_cast<const f32x4*>(Wd + (size_t)a * 4096);
        const f32x4* rb = reinterpret_cast<const f32x4*>(bd);
        for (int j = t; j < 1024; j += 256) {
            f32x4 u = ra[j], v = rb[j];
            p += u[0] * v[0] + u[1] * v[1] + u[2] * v[2] + u[3] * v[3];
        }
    } else {
        const f32x4* rb = reinterpret_cast<const f32x4*>(bd);
        for (int j = t; j < 1024; j += 256) {
            f32x4 v = rb[j];
            p += v[0] * v[0] + v[1] * v[1] + v[2] * v[2] + v[3] * v[3];
        }
    }
    red[t] = p;
    __syncthreads();
    for (int s = 128; s > 0; s >>= 1) { if (t < s) red[t] += red[t + s]; __syncthreads(); }
    if (t == 0) {
        if (b < 4096) G[b] = red[0];
        else if (b < 4160) hv[b - 4096] = red[0];
        else ev[0] = red[0];
    }
}

// ---------------- main GEMM: 2-phase template + coalesced LDS-staged writeback
__global__ __launch_bounds__(256, 4) void gemm_kernel(const float* __restrict__ x,
        const unsigned char* __restrict__ Bp, float* __restrict__ Pp,
        int steps, int kslice, int ppstride) {
    __shared__ __align__(16) char lds[40960];    // A: 2x8192 @0, B: 2x12288 @16384; C-tile reuse
    char* ldsA = lds;
    char* ldsB = lds + 16384;
    const int tid = threadIdx.x;
    const int lane = tid & 63, w = tid >> 6;
    const int wm = w >> 1, wn = w & 1;           // 2m x 2n waves
    const int l15 = lane & 15, kg = lane >> 4;
    const int rowbase = blockIdx.x * 64;
    const int ks = blockIdx.y;

    const float* xA[2];
    {
        int rsub = lane >> 3;
        int co = ((lane & 7) ^ rsub) << 2;
#pragma unroll
        for (int i = 0; i < 2; ++i)
            xA[i] = x + (size_t)(rowbase + (w * 2 + i) * 8 + rsub) * 4096
                      + (size_t)ks * kslice + co;
    }
    const unsigned char* gB0 = Bp + (size_t)(ks * steps) * 12288
                                  + (size_t)(w * 3) * 1024 + (size_t)lane * 16;

    f32x4 acc[2][5];
#pragma unroll
    for (int mi = 0; mi < 2; ++mi)
#pragma unroll
        for (int ni = 0; ni < 5; ++ni) acc[mi][ni] = (f32x4){0.f, 0.f, 0.f, 0.f};
    float sxa0 = 0.f, sxa1 = 0.f;

#define STAGE(buf, tt) do { \
        _Pragma("unroll") \
        for (int i_ = 0; i_ < 2; ++i_) \
            gll16(xA[i_] + (tt) * 32, ldsA + (buf) * 8192 + (w * 2 + i_) * 1024); \
        _Pragma("unroll") \
        for (int j_ = 0; j_ < 3; ++j_) \
            gll16(gB0 + (size_t)(tt) * 12288 + j_ * 1024, \
                  ldsB + (buf) * 12288 + (w * 3 + j_) * 1024); \
    } while (0)

#define COMPUTE(buf) do { \
        char* A0 = ldsA + (buf) * 8192; \
        char* B0 = ldsB + (buf) * 12288; \
        bf16x8 bfr[5]; \
        _Pragma("unroll") \
        for (int ni_ = 0; ni_ < 5; ++ni_) { \
            int col_ = wn * 80 + ni_ * 16 + l15; \
            bfr[ni_] = *reinterpret_cast<const bf16x8*>( \
                B0 + col_ * 64 + ((kg ^ (col_ & 3)) << 4)); \
        } \
        _Pragma("unroll") \
        for (int mi_ = 0; mi_ < 2; ++mi_) { \
            int row_ = wm * 32 + mi_ * 16 + l15; \
            int e0_ = (kg << 1) ^ (row_ & 7); \
            f32x4 fa_ = *reinterpret_cast<const f32x4*>(A0 + row_ * 128 + (e0_ << 4)); \
            f32x4 fb_ = *reinterpret_cast<const f32x4*>(A0 + row_ * 128 + ((e0_ ^ 1) << 4)); \
            bf16x8 af_; \
            af_[0] = f2bf_s(fa_[0]); af_[1] = f2bf_s(fa_[1]); \
            af_[2] = f2bf_s(fa_[2]); af_[3] = f2bf_s(fa_[3]); \
            af_[4] = f2bf_s(fb_[0]); af_[5] = f2bf_s(fb_[1]); \
            af_[6] = f2bf_s(fb_[2]); af_[7] = f2bf_s(fb_[3]); \
            if (wn == 0) { \
                float ss_ = fa_[0]*fa_[0] + fa_[1]*fa_[1] + fa_[2]*fa_[2] + fa_[3]*fa_[3] \
                          + fb_[0]*fb_[0] + fb_[1]*fb_[1] + fb_[2]*fb_[2] + fb_[3]*fb_[3]; \
                if (mi_ == 0) sxa0 += ss_; else sxa1 += ss_; \
            } \
            _Pragma("unroll") \
            for (int ni_ = 0; ni_ < 5; ++ni_) \
                acc[mi_][ni_] = __builtin_amdgcn_mfma_f32_16x16x32_bf16( \
                    af_, bfr[ni_], acc[mi_][ni_], 0, 0, 0); \
        } \
    } while (0)

    STAGE(0, 0);
    asm volatile("s_waitcnt vmcnt(0)" ::: "memory");
    __builtin_amdgcn_s_barrier();
    asm volatile("" ::: "memory");
    int cur = 0;
    for (int t = 0; t < steps - 1; ++t) {
        STAGE(cur ^ 1, t + 1);
        asm volatile("s_waitcnt vmcnt(5)" ::: "memory");
        __builtin_amdgcn_s_barrier();
        asm volatile("" ::: "memory");
        COMPUTE(cur);
        asm volatile("" ::: "memory");
        __builtin_amdgcn_s_barrier();
        cur ^= 1;
    }
    asm volatile("s_waitcnt vmcnt(0)" ::: "memory");
    __builtin_amdgcn_s_barrier();
    asm volatile("" ::: "memory");
    COMPUTE(cur);
#undef STAGE
#undef COMPUTE

    // reduce sx2 across kg groups (lanes 0-15 end with row totals)
    sxa0 += __shfl_xor(sxa0, 16); sxa0 += __shfl_xor(sxa0, 32);
    sxa1 += __shfl_xor(sxa1, 16); sxa1 += __shfl_xor(sxa1, 32);

    // ---- coalesced writeback: acc -> LDS C-tile [64][148], then full rows out
    __syncthreads();
    float* C = reinterpret_cast<float*>(lds);
#pragma unroll
    for (int mi = 0; mi < 2; ++mi)
#pragma unroll
        for (int ni = 0; ni < 5; ++ni) {
            int col = wn * 80 + ni * 16 + l15;
            if (col < 148 && col != 130) {
#pragma unroll
                for (int i2 = 0; i2 < 4; ++i2)
                    C[(wm * 32 + mi * 16 + kg * 4 + i2) * 148 + col] = acc[mi][ni][i2];
            }
        }
    if (wn == 0 && lane < 16) {
        C[(wm * 32 + lane) * 148 + 130] = sxa0;
        C[(wm * 32 + 16 + lane) * 148 + 130] = sxa1;
    }
    __syncthreads();
    // 64 rows x 36 float4 = 2304 stores, 9 per thread, consecutive threads -> consecutive 16B
#pragma unroll
    for (int i = 0; i < 9; ++i) {
        int idx = tid + 256 * i;
        int r = idx / 36, c4 = idx % 36;
        f32x4 v = *reinterpret_cast<const f32x4*>(C + r * 148 + c4 * 4);
        *reinterpret_cast<f32x4*>(Pp + (size_t)(rowbase + r) * ppstride + ks * 144 + c4 * 4) = v;
    }
}

// ---------------- phase 2: plain [64][64] G, XOR-permuted conflict-free matvec
__global__ __launch_bounds__(256) void phase2_kernel(const float* __restrict__ Pp,
        const float* __restrict__ noise, const float* __restrict__ bem,
        const float* __restrict__ Wds, const float* __restrict__ bes_p,
        const float* __restrict__ bds_p, const float* __restrict__ G,
        const float* __restrict__ hv, const float* __restrict__ ev,
        float* __restrict__ partial, int ksplit, int ppstride) {
    __shared__ float Gl[4096];                    // [64][64] plain
    __shared__ float hl[64], wl[64], beml[64];
    __shared__ float zs[4][64];
    __shared__ float red[4];
    int tid = threadIdx.x;
    for (int i = tid; i < 4096; i += 256) Gl[i] = G[i];
    if (tid < 64) { hl[tid] = hv[tid]; wl[tid] = Wds[tid]; beml[tid] = bem[tid]; }
    __syncthreads();
    float bes = bes_p[0], bds = bds_p[0], e = ev[0];
    int wid = tid >> 6, k = tid & 63;
    const int sw = (k & 15) << 2;                 // per-lane permuted block order
    float wacc = 0.f;
#pragma unroll
    for (int rr = 0; rr < 8; ++rr) {
        int row = blockIdx.x * 32 + wid * 8 + rr;
        const float* base = Pp + (size_t)row * ppstride;
        float zmu = beml[k], ck = 0.f, se = bes, dd = 0.f, sx2 = 0.f;
        for (int s = 0; s < ksplit; ++s) {
            const float* b2 = base + s * 144;
            zmu += b2[k]; ck += b2[64 + k];
            se += b2[128]; dd += b2[129]; sx2 += b2[130];
        }
        float nz = noise[(size_t)row * 64 + k];
        float s2 = se * se;
        float z = fmaf(s2, nz, zmu);
        zs[wid][k] = z;                            // wave-synchronous broadcast
        float t0 = 0.f, t1 = 0.f, t2 = 0.f, t3 = 0.f;
        const float* gr = &Gl[k * 64];
        const float* zr = &zs[wid][0];
#pragma unroll
        for (int jb = 0; jb < 16; ++jb) {
            int p = (jb * 4) ^ sw;                 // banks tile 2/bank per quarter-wave
            f32x4 gv = *reinterpret_cast<const f32x4*>(gr + p);
            f32x4 zv = *reinterpret_cast<const f32x4*>(zr + p);
            t0 = fmaf(gv[0], zv[0], t0); t1 = fmaf(gv[1], zv[1], t1);
            t2 = fmaf(gv[2], zv[2], t2); t3 = fmaf(gv[3], zv[3], t3);
        }
        float t = (t0 + t1) + (t2 + t3);           // (Gz)_k via symmetry
        float ra = z * z;
        float rb = nz * nz;
        float rc = z * wl[k];
        float rd = z * ck;
        float re = z * fmaf(2.f, hl[k], t);
#pragma unroll
        for (int d = 1; d < 64; d <<= 1) {
            ra += __shfl_xor(ra, d); rb += __shfl_xor(rb, d);
            rc += __shfl_xor(rc, d); rd += __shfl_xor(rd, d);
            re += __shfl_xor(re, d);
        }
        float sdec = rc + bds;
        float xxmu = rd + dd;
        float xmu2 = re + e;
        float sq_lik = sx2 - 2.f * xxmu + xmu2;
        float vz = s2 * s2;
        float sd2 = sdec * sdec;
        float vx = sd2 * sd2;
        wacc += 0.5f * (4096.f * LOG2PI + 4096.f * __logf(vx) + sq_lik / vx
                        + ra - 64.f * __logf(vz) - rb);
    }
    if (k == 0) red[wid] = wacc;
    __syncthreads();
    if (tid == 0) partial[blockIdx.x] = red[0] + red[1] + red[2] + red[3];
}

__global__ __launch_bounds__(256) void final_reduce_kernel(const float* __restrict__ partial,
                                                           float* __restrict__ out) {
    __shared__ float red[4];
    int tid = threadIdx.x;
    float v = 0.f;
    for (int i = tid; i < 512; i += 256) v += partial[i];
#pragma unroll
    for (int d = 1; d < 64; d <<= 1) v += __shfl_xor(v, d);
    if ((tid & 63) == 0) red[tid >> 6] = v;
    __syncthreads();
    if (tid == 0) out[0] = red[0] + red[1] + red[2] + red[3];
}

extern "C" void kernel_launch(void* const* d_in, const int* in_sizes, int n_in,
                              void* d_out, int out_size, void* d_ws, size_t ws_size,
                              hipStream_t stream) {
    const float* x     = (const float*)d_in[0];
    const float* noise = (const float*)d_in[1];
    const float* We    = (const float*)d_in[2];
    const float* bem   = (const float*)d_in[3];
    const float* Wes   = (const float*)d_in[4];
    const float* bes   = (const float*)d_in[5];
    const float* Wd    = (const float*)d_in[6];
    const float* bdm   = (const float*)d_in[7];
    const float* Wds   = (const float*)d_in[8];
    const float* bds   = (const float*)d_in[9];

    int ksplit = (ws_size >= 39340544ull) ? 4 : (ws_size >= 20466176ull ? 2 : 1);
    int steps = 128 / ksplit;
    int kslice = steps * 32;
    int ppstride = ksplit * 144;

    char* ws = (char*)d_ws;
    size_t ppbytes = (size_t)16384 * ppstride * 4;
    float* Pp           = (float*)ws;
    unsigned char* Bp   = (unsigned char*)(ws + ppbytes);
    float* G            = (float*)(ws + ppbytes + 1572864);
    float* hv           = (float*)(ws + ppbytes + 1572864 + 16384);
    float* ev           = (float*)(ws + ppbytes + 1572864 + 16640);
    float* partial      = (float*)(ws + ppbytes + 1572864 + 16896);

    pack_b_kernel<<<128, 256, 0, stream>>>(We, Wes, Wd, bdm, Bp);
    prep_g_kernel<<<4161, 256, 0, stream>>>(Wd, bdm, G, hv, ev);
    gemm_kernel<<<dim3(256, ksplit), 256, 0, stream>>>(x, Bp, Pp, steps, kslice, ppstride);
    phase2_kernel<<<512, 256, 0, stream>>>(Pp, noise, bem, Wds, bes, bds, G, hv, ev,
                                           partial, ksplit, ppstride);
    final_reduce_kernel<<<1, 256, 0, stream>>>(partial, (float*)d_out);
}